// Round 1
// baseline (262.656 us; speedup 1.0000x reference)
//
#include <hip/hip_runtime.h>

typedef __attribute__((ext_vector_type(8))) short bf16x8;
typedef __attribute__((ext_vector_type(4))) float f32x4;

#define GLOAD_LDS16(gp, lp)                                                   \
  __builtin_amdgcn_global_load_lds(                                           \
      (const __attribute__((address_space(1))) void*)(gp),                    \
      (__attribute__((address_space(3))) void*)(lp), 16, 0, 0)

__device__ inline unsigned short f2bf(float f) {
  union { float f; unsigned u; } a; a.f = f;
  unsigned u = a.u;
  return (unsigned short)((u + 0x7fffu + ((u >> 16) & 1u)) >> 16);  // RNE
}

__global__ void cvt_f32_bf16(const float* __restrict__ in,
                             unsigned short* __restrict__ out, int n4) {
  int i = blockIdx.x * blockDim.x + threadIdx.x;
  int stride = gridDim.x * blockDim.x;
  for (; i < n4; i += stride) {
    float4 v = reinterpret_cast<const float4*>(in)[i];
    ushort4 o;
    o.x = f2bf(v.x); o.y = f2bf(v.y); o.z = f2bf(v.z); o.w = f2bf(v.w);
    reinterpret_cast<ushort4*>(out)[i] = o;
  }
}

// Implicit GEMM: M=123008 (=32*62*62), N=256, K=1152 (=9 taps * 128 ch).
// Block: 512 thr (8 waves, 2x4 wave grid), BM=128, BN=256, BK=64, 18 K-steps.
#define BM 128
#define BK 64

__global__ __launch_bounds__(512) void conv_gemm(
    const unsigned short* __restrict__ A,   // bf16 input NHWC (32,64,64,128)
    const unsigned short* __restrict__ Bw,  // bf16 w (256,1152)  == B^T
    const float* __restrict__ bias,         // fp32 (256)
    float* __restrict__ out)                // fp32 (123008,256)
{
  __shared__ unsigned short sA[BM * BK];   // 16 KB
  __shared__ unsigned short sB[256 * BK];  // 32 KB

  const int tid = threadIdx.x;
  const int bm = blockIdx.x;

  // ---- staging coords: thread stages rows {r0, r0+64} of A-tile, seg s ----
  const int r0 = tid >> 3;        // 0..63
  const int s  = tid & 7;         // 16B segment within a 128B row
  const int sp = s ^ (r0 & 7);    // source-side XOR swizzle (rule #21/T2);
                                  // +64/+128 row offsets are mult. of 8 -> same sp

  // decompose the two M-rows into input pixel indices
  int m0 = bm * BM + r0;
  int m1 = m0 + 64;
  int n0 = m0 / 3844, rem0 = m0 % 3844;
  int n1 = m1 / 3844, rem1 = m1 % 3844;
  const int p0 = (n0 * 64 + rem0 / 62) * 64 + rem0 % 62;
  const int p1 = (n1 * 64 + rem1 / 62) * 64 + rem1 % 62;

  const int wv   = tid >> 6;
  const int lane = tid & 63;
  const int wm   = wv >> 2;   // 0..1  (64-row wave tile)
  const int wn   = wv & 3;    // 0..3  (64-col wave tile)
  const int l15  = lane & 15;
  const int lhi  = lane >> 4;

  f32x4 acc[4][4];
  #pragma unroll
  for (int i = 0; i < 4; ++i)
    #pragma unroll
    for (int j = 0; j < 4; ++j)
      acc[i][j] = (f32x4){0.f, 0.f, 0.f, 0.f};

  for (int step = 0; step < 18; ++step) {
    const int pos = step >> 1;
    const int kh = pos / 3, kw = pos % 3;
    const int c0 = (step & 1) << 6;        // channel half: 0 or 64
    const int dpix = kh * 64 + kw;

    __syncthreads();   // previous compute done before overwrite

    // ---- stage A tile: 128 rows x 64 bf16, 2 issues/thread ----
    {
      const unsigned short* g0 = A + (size_t)(p0 + dpix) * 128 + c0 + sp * 8;
      const unsigned short* g1 = A + (size_t)(p1 + dpix) * 128 + c0 + sp * 8;
      GLOAD_LDS16(g0, &sA[tid * 8]);
      GLOAD_LDS16(g1, &sA[(tid + 512) * 8]);
    }
    // ---- stage B tile: 256 rows x 64 bf16, 4 issues/thread ----
    {
      const int dk = pos * 128 + c0 + sp * 8;
      #pragma unroll
      for (int it = 0; it < 4; ++it) {
        const int f = it * 64 + r0;        // f&7 == r0&7 -> same sp
        GLOAD_LDS16(Bw + (size_t)f * 1152 + dk, &sB[(it * 512 + tid) * 8]);
      }
    }
    __syncthreads();   // compiler drains vmcnt(0) before the barrier

    #pragma unroll
    for (int kk = 0; kk < 2; ++kk) {
      const int t = kk * 4 + lhi;          // 16B segment index for this frag
      bf16x8 af[4], bfr[4];
      #pragma unroll
      for (int i = 0; i < 4; ++i) {
        const int row = wm * 64 + i * 16 + l15;
        af[i] = *reinterpret_cast<const bf16x8*>(
            reinterpret_cast<const char*>(sA) + row * 128 + ((t ^ (row & 7)) * 16));
      }
      #pragma unroll
      for (int j = 0; j < 4; ++j) {
        const int fl = wn * 64 + j * 16 + l15;
        bfr[j] = *reinterpret_cast<const bf16x8*>(
            reinterpret_cast<const char*>(sB) + fl * 128 + ((t ^ (fl & 7)) * 16));
      }
      #pragma unroll
      for (int i = 0; i < 4; ++i)
        #pragma unroll
        for (int j = 0; j < 4; ++j)
          acc[i][j] = __builtin_amdgcn_mfma_f32_16x16x32_bf16(af[i], bfr[j],
                                                              acc[i][j], 0, 0, 0);
    }
  }

  // ---- epilogue: bias + store fp32; C/D map: col=lane&15, row=(lane>>4)*4+r ----
  const int colb = wn * 64 + l15;
  #pragma unroll
  for (int j = 0; j < 4; ++j) {
    const float bv = bias[colb + j * 16];
    #pragma unroll
    for (int i = 0; i < 4; ++i) {
      const int rowb = bm * BM + wm * 64 + i * 16 + lhi * 4;
      #pragma unroll
      for (int r = 0; r < 4; ++r)
        out[(size_t)(rowb + r) * 256 + colb + j * 16] = acc[i][j][r] + bv;
    }
  }
}

extern "C" void kernel_launch(void* const* d_in, const int* in_sizes, int n_in,
                              void* d_out, int out_size, void* d_ws, size_t ws_size,
                              hipStream_t stream) {
  const float* inp = (const float*)d_in[0];   // (32,64,64,128) fp32
  const float* w   = (const float*)d_in[1];   // (256,1152) fp32
  const float* b   = (const float*)d_in[2];   // (256) fp32
  float* out = (float*)d_out;                 // (123008,256) fp32

  unsigned short* wsA = (unsigned short*)d_ws;          // bf16 input copy
  unsigned short* wsB = wsA + 16777216;                 // bf16 weight copy

  cvt_f32_bf16<<<2048, 256, 0, stream>>>(inp, wsA, 16777216 / 4);
  cvt_f32_bf16<<<288, 256, 0, stream>>>(w, wsB, 294912 / 4);
  conv_gemm<<<961, 512, 0, stream>>>(wsA, wsB, b, out);
}